// Round 12
// baseline (381.156 us; speedup 1.0000x reference)
//
#include <hip/hip_runtime.h>

// 2-layer LSTM (HID=10), B=2048, T=1024 main + F=64 future steps.
//
// Round 19: DPP-ring recurrences inside the r18 4-role pipeline.
// r18 post-mortem: 2 waves/SIMD changed nothing (VALUBusy ~51%, wall ~600
// cyc/step) -> each block's wall = T x serial chain; co-resident waves can't
// shorten it. Cross-round isolation: r11 (DPP bcast) exposed ~240 cyc chain,
// r12 (ds_swizzle bcast) ~455 -> the in-chain swizzle hop costs ~200 cyc
// (DS-pipe latency) vs DPP's ~8 (VALU-forwarded). Change ONLY the serial
// waves' cross-lane mechanism:
//  - W0 (cell1) / W2 (cell2): h kept in rotated form hr[r]; new h rotated by
//    15 parallel v_mov_dpp row_ror (r11-verified, incl direction probe);
//    dots become 16-term padded pre-rotated weight tables (+issue, -chain).
//  - W1 (U-dots) / W3 (head): unchanged throughput stages (uniform LDS
//    reads, no cross-lane in chain).
//  - W3 future tail: swizzle fstep, flat tables built AFTER the main loop
//    (keeps main-loop register pressure down).
// Skeleton (rings, skew 1/2/3, one barrier/chunk, handoffs) verbatim r18.
// New bound: 2 same-role waves/SIMD x ~150 issue-cyc -> ~300 cyc/step.

#define NB 512
#define TMAIN 1024
#define HID 10
#define KCH 16
#define NCH (TMAIN / KCH)   // 64 chunks

typedef float v2f __attribute__((ext_vector_type(2)));
typedef float v4f __attribute__((ext_vector_type(4)));

#define PIN2(v) asm volatile("" : "+v"(v))
#define PIN(v)  asm volatile("" : "+v"(v))

__device__ __forceinline__ float rcp_(float v)  { return __builtin_amdgcn_rcpf(v); }
__device__ __forceinline__ float exp2_(float v) { return __builtin_amdgcn_exp2f(v); }
__device__ __forceinline__ v2f mk2(float x, float y) { v2f r; r.x = x; r.y = y; return r; }
__device__ __forceinline__ v2f pfma2(v2f a, v2f b, v2f c) { return __builtin_elementwise_fma(a, b, c); }

template<int R>
__device__ __forceinline__ float rorf(float v) {   // DPP row_ror:R (16-lane rows)
    return __int_as_float(__builtin_amdgcn_update_dpp(
        0, __float_as_int(v), 0x120 + R, 0xF, 0xF, true));
}
__device__ __forceinline__ void rot16(float h, float* hr) {
    hr[0] = h;
    hr[1]  = rorf<1>(h);  hr[2]  = rorf<2>(h);  hr[3]  = rorf<3>(h);
    hr[4]  = rorf<4>(h);  hr[5]  = rorf<5>(h);  hr[6]  = rorf<6>(h);
    hr[7]  = rorf<7>(h);  hr[8]  = rorf<8>(h);  hr[9]  = rorf<9>(h);
    hr[10] = rorf<10>(h); hr[11] = rorf<11>(h); hr[12] = rorf<12>(h);
    hr[13] = rorf<13>(h); hr[14] = rorf<14>(h); hr[15] = rorf<15>(h);
}
template<int J>
__device__ __forceinline__ float bc16(float v) {   // broadcast lane J within 16-group
    return __int_as_float(__builtin_amdgcn_ds_swizzle(__float_as_int(v), (J << 5) | 0x10));
}
__device__ __forceinline__ void bcast10(float h, float* hb) {
    hb[0] = bc16<0>(h); hb[1] = bc16<1>(h); hb[2] = bc16<2>(h); hb[3] = bc16<3>(h);
    hb[4] = bc16<4>(h); hb[5] = bc16<5>(h); hb[6] = bc16<6>(h); hb[7] = bc16<7>(h);
    hb[8] = bc16<8>(h); hb[9] = bc16<9>(h);
}

__global__ __launch_bounds__(256)
void lstm2_kernel(
    const float* __restrict__ x,
    const float* __restrict__ Wih1, const float* __restrict__ Whh1,
    const float* __restrict__ bih1, const float* __restrict__ bhh1,
    const float* __restrict__ Wih2, const float* __restrict__ Whh2,
    const float* __restrict__ bih2, const float* __restrict__ bhh2,
    const float* __restrict__ Wlin, const float* __restrict__ blin,
    const int* __restrict__ futp,
    float* __restrict__ out)
{
    const int tid  = threadIdx.x;
    const int wid  = tid >> 6;           // 0=cell1 1=U 2=cell2 3=head
    const int lane = tid & 63;
    const int e    = lane >> 4;          // element 0..3
    const int u    = lane & 15;          // unit (valid < 10)
    const int ge   = blockIdx.x * 4 + e;
    const int F    = futp[0];
    const int OUTW = TMAIN + F;

    __shared__ __align__(16) float ringH1[2][KCH][64];
    __shared__ __align__(16) v4f   ringU [2][KCH][64];
    __shared__ __align__(16) float ringH2[2][KCH][64];
    __shared__ __align__(16) float stC1[64], stH1[64], stC2[64], stH2[64];

    const bool uok = (u < HID);
    const int  uu  = uok ? u : 0;
    const int  Ri  = 0 * HID + uu;
    const int  Rf  = 1 * HID + uu;
    const int  Rg  = 2 * HID + uu;
    const int  Ro  = 3 * HID + uu;

    const float tK = 2.8853900817779268f;    //  2*log2(e)
    const float sK = -1.4426950408889634f;   // -log2(e)
    const float mu = uok ? 1.f : 0.f;
    const float sKm = mu * sK;
    const float tKm = mu * tK;

    // DPP direction probe (r11-verified): does row_ror:1 deliver u+1 or u-1?
    const int rot1 = __builtin_amdgcn_update_dpp(0, u, 0x121, 0xF, 0xF, true);
    const bool dplus = (rot1 == ((u + 1) & 15));

    // ---- role-specific tables ----
    v2f wrot_if[16], wrot_go[16];        // W0: Whh1-rot ; W2: Whh2-rot
    v2f w2i_if[10], w2i_go[10];          // W1
    v2f wlp[5];                          // W3 head
    v2f wx_if = mk2(0.f, 0.f), wx_go = wx_if;
    v2f b1_if = wx_if, b1_go = wx_if, b2_if = wx_if, b2_go = wx_if;
    float bl = blin[0];

    if (wid == 0 || wid == 2) {
        const float* W = (wid == 0) ? Whh1 : Whh2;
        #pragma unroll
        for (int r = 0; r < 16; ++r) {
            int jr = (u + (dplus ? r : 16 - r)) & 15;
            int jc = (jr < HID) ? jr : 0;
            float m = (uok && jr < HID) ? 1.f : 0.f;
            wrot_if[r] = mk2(m * sK * W[Ri*HID + jc], m * sK * W[Rf*HID + jc]);
            wrot_go[r] = mk2(m * tK * W[Rg*HID + jc], m * sK * W[Ro*HID + jc]);
        }
        #pragma unroll
        for (int r = 0; r < 16; ++r) { PIN2(wrot_if[r]); PIN2(wrot_go[r]); }
    }
    if (wid == 0) {
        wx_if = mk2(sKm * Wih1[Ri], sKm * Wih1[Rf]);
        wx_go = mk2(tKm * Wih1[Rg], sKm * Wih1[Ro]);
        b1_if = mk2(sKm * (bih1[Ri] + bhh1[Ri]), sKm * (bih1[Rf] + bhh1[Rf]));
        b1_go = mk2(tKm * (bih1[Rg] + bhh1[Rg]), sKm * (bih1[Ro] + bhh1[Ro]));
        PIN2(wx_if); PIN2(wx_go); PIN2(b1_if); PIN2(b1_go);
    }
    if (wid == 1) {
        #pragma unroll
        for (int j = 0; j < HID; ++j) {
            w2i_if[j] = mk2(sKm * Wih2[Ri*HID + j], sKm * Wih2[Rf*HID + j]);
            w2i_go[j] = mk2(tKm * Wih2[Rg*HID + j], sKm * Wih2[Ro*HID + j]);
        }
        b2_if = mk2(sKm * (bih2[Ri] + bhh2[Ri]), sKm * (bih2[Rf] + bhh2[Rf]));
        b2_go = mk2(tKm * (bih2[Rg] + bhh2[Rg]), sKm * (bih2[Ro] + bhh2[Ro]));
        #pragma unroll
        for (int j = 0; j < HID; ++j) { PIN2(w2i_if[j]); PIN2(w2i_go[j]); }
        PIN2(b2_if); PIN2(b2_go);
    }
    if (wid == 3) {
        #pragma unroll
        for (int k = 0; k < 5; ++k) { wlp[k] = mk2(Wlin[2*k], Wlin[2*k + 1]); PIN2(wlp[k]); }
    }

    auto ctanh_ = [&](float cs) -> float {
        return fmaf(-2.0f, rcp_(1.0f + exp2_(cs)), 1.0f);
    };
    auto cellup2 = [&](v2f p_if, v2f p_go, float& c) -> float {   // verbatim r17
        v2f q_if, q_go;
        q_if.x = rcp_(1.0f + exp2_(p_if.x));
        q_if.y = rcp_(1.0f + exp2_(p_if.y));
        q_go.x = rcp_(1.0f + exp2_(p_go.x));
        q_go.y = rcp_(1.0f + exp2_(p_go.y));
        float g = fmaf(-2.0f * tK, q_go.x, tK);
        c = fmaf(q_if.y, c, q_if.x * g);
        return q_go.y * ctanh_(c);
    };
    auto dotp = [&](const v2f* w, const float* hb, v2f init) -> v2f {  // 10-term
        v2f P = pfma2(w[0], mk2(hb[0], hb[0]), init);
        v2f Q = w[1] * mk2(hb[1], hb[1]);
        #pragma unroll
        for (int j = 2; j < HID; j += 2) {
            P = pfma2(w[j],     mk2(hb[j],     hb[j]),     P);
            Q = pfma2(w[j + 1], mk2(hb[j + 1], hb[j + 1]), Q);
        }
        return P + Q;
    };
    auto dot16rot = [&](const v2f* w, const float* hr, v2f init) -> v2f {  // 16-term rot
        v2f P = pfma2(w[0], mk2(hr[0], hr[0]), init);
        v2f Q = w[1] * mk2(hr[1], hr[1]);
        #pragma unroll
        for (int r = 2; r < 16; r += 2) {
            P = pfma2(w[r],     mk2(hr[r],     hr[r]),     P);
            Q = pfma2(w[r + 1], mk2(hr[r + 1], hr[r + 1]), Q);
        }
        return P + Q;
    };
    auto loadhb = [&](const float* base, float* hb) {   // uniform bcast read, 10 floats
        v4f a = *(const v4f*)(base);
        v4f b = *(const v4f*)(base + 4);
        v2f c = *(const v2f*)(base + 8);
        hb[0] = a.x; hb[1] = a.y; hb[2] = a.z; hb[3] = a.w;
        hb[4] = b.x; hb[5] = b.y; hb[6] = b.z; hb[7] = b.w;
        hb[8] = c.x; hb[9] = c.y;
    };

    // ---- state ----
    float c1 = 0.f, c2 = 0.f, h1last = 0.f, h2last = 0.f, yprev = 0.f;
    float h1r[16], h2r[16];              // rotated h (W0 / W2)
    float h2b[10];                       // W3 head input
    #pragma unroll
    for (int r = 0; r < 16; ++r) { h1r[r] = 0.f; h2r[r] = 0.f; }
    #pragma unroll
    for (int j = 0; j < HID; ++j) h2b[j] = 0.f;

    auto head_ = [&]() -> float {
        v2f Y = pfma2(wlp[0], mk2(h2b[0], h2b[1]), mk2(bl, 0.f));
        #pragma unroll
        for (int k = 1; k < 5; ++k)
            Y = pfma2(wlp[k], mk2(h2b[2*k], h2b[2*k + 1]), Y);
        return Y.x + Y.y;
    };

    // W0 step: cell1 via rot dots, rotate new h1, stash lane value
    auto pstep0 = [&](float xt, float* hslot) -> float {
        v2f A_if = dot16rot(wrot_if, h1r, pfma2(wx_if, mk2(xt, xt), b1_if));
        v2f A_go = dot16rot(wrot_go, h1r, pfma2(wx_go, mk2(xt, xt), b1_go));
        float h1n = cellup2(A_if, A_go, c1);
        rot16(h1n, h1r);
        hslot[lane] = h1n;
        return h1n;
    };

    const float4* xrow = (const float4*)(x + (size_t)ge * TMAIN);
    float4* orow = (float4*)(out + (size_t)ge * OUTW);   // OUTW=1088, 16B rows

    float4 z4 = make_float4(0.f, 0.f, 0.f, 0.f);
    float4 xq0 = z4, xq1 = z4, xq2 = z4, xq3 = z4;
    if (wid == 0) { xq0 = xrow[0]; xq1 = xrow[1]; xq2 = xrow[2]; xq3 = xrow[3]; }

    // ---- main pipeline: 67 iterations; W_k processes chunk c-k ----
    #pragma unroll 1
    for (int c = 0; c <= NCH + 2; ++c) {
        if (wid == 0) {
            if (c < NCH) {
                float4 xn0 = z4, xn1 = z4, xn2 = z4, xn3 = z4;
                if (c + 1 < NCH) {
                    xn0 = xrow[(c+1)*4+0]; xn1 = xrow[(c+1)*4+1];
                    xn2 = xrow[(c+1)*4+2]; xn3 = xrow[(c+1)*4+3];
                }
                float* hs = &ringH1[c & 1][0][0];
                h1last = pstep0(xq0.x, hs + 0*64);  h1last = pstep0(xq0.y, hs + 1*64);
                h1last = pstep0(xq0.z, hs + 2*64);  h1last = pstep0(xq0.w, hs + 3*64);
                h1last = pstep0(xq1.x, hs + 4*64);  h1last = pstep0(xq1.y, hs + 5*64);
                h1last = pstep0(xq1.z, hs + 6*64);  h1last = pstep0(xq1.w, hs + 7*64);
                h1last = pstep0(xq2.x, hs + 8*64);  h1last = pstep0(xq2.y, hs + 9*64);
                h1last = pstep0(xq2.z, hs + 10*64); h1last = pstep0(xq2.w, hs + 11*64);
                h1last = pstep0(xq3.x, hs + 12*64); h1last = pstep0(xq3.y, hs + 13*64);
                h1last = pstep0(xq3.z, hs + 14*64); h1last = pstep0(xq3.w, hs + 15*64);
                if (c == NCH - 1) { stC1[lane] = c1; stH1[lane] = h1last; }
                xq0 = xn0; xq1 = xn1; xq2 = xn2; xq3 = xn3;
            }
        } else if (wid == 1) {
            const int cc = c - 1;
            if (cc >= 0 && cc < NCH) {
                const float* hs = &ringH1[cc & 1][0][0];
                v4f* us = &ringU[cc & 1][0][0];
                #pragma unroll
                for (int t = 0; t < KCH; ++t) {
                    float hb[10];
                    loadhb(hs + t*64 + e*16, hb);
                    v2f U_if = dotp(w2i_if, hb, b2_if);
                    v2f U_go = dotp(w2i_go, hb, b2_go);
                    v4f U; U.x = U_if.x; U.y = U_if.y; U.z = U_go.x; U.w = U_go.y;
                    us[t*64 + lane] = U;
                }
            }
        } else if (wid == 2) {
            const int cc = c - 2;
            if (cc >= 0 && cc < NCH) {
                const v4f* us = &ringU[cc & 1][0][0];
                float* h2s = &ringH2[cc & 1][0][0];
                #pragma unroll
                for (int t = 0; t < KCH; ++t) {
                    v4f U = us[t*64 + lane];
                    v2f V_if = dot16rot(wrot_if, h2r, mk2(U.x, U.y));
                    v2f V_go = dot16rot(wrot_go, h2r, mk2(U.z, U.w));
                    float h2n = cellup2(V_if, V_go, c2);
                    rot16(h2n, h2r);
                    h2s[t*64 + lane] = h2n;
                    h2last = h2n;
                }
                if (cc == NCH - 1) { stC2[lane] = c2; stH2[lane] = h2last; }
            }
        } else {
            const int cc = c - 3;
            if (cc >= 0 && cc < NCH) {
                const float* h2s = &ringH2[cc & 1][0][0];
                #pragma unroll
                for (int q = 0; q < 4; ++q) {
                    float y0, y1, y2, y3;
                    loadhb(h2s + (q*4 + 0)*64 + e*16, h2b); y0 = head_();
                    loadhb(h2s + (q*4 + 1)*64 + e*16, h2b); y1 = head_();
                    loadhb(h2s + (q*4 + 2)*64 + e*16, h2b); y2 = head_();
                    loadhb(h2s + (q*4 + 3)*64 + e*16, h2b); y3 = head_();
                    if (u == 0) orow[cc*4 + q] = make_float4(y0, y1, y2, y3);
                    yprev = y3;
                }
            }
        }
        __syncthreads();
    }

    // ---- future loop: W3 only; flat tables built HERE (pressure isolation) ----
    if (wid == 3) {
        v2f f1_if[10], f1_go[10], f2i_if[10], f2i_go[10], f2h_if[10], f2h_go[10];
        #pragma unroll
        for (int j = 0; j < HID; ++j) {
            f1_if[j]  = mk2(sKm * Whh1[Ri*HID + j], sKm * Whh1[Rf*HID + j]);
            f1_go[j]  = mk2(tKm * Whh1[Rg*HID + j], sKm * Whh1[Ro*HID + j]);
            f2i_if[j] = mk2(sKm * Wih2[Ri*HID + j], sKm * Wih2[Rf*HID + j]);
            f2i_go[j] = mk2(tKm * Wih2[Rg*HID + j], sKm * Wih2[Ro*HID + j]);
            f2h_if[j] = mk2(sKm * Whh2[Ri*HID + j], sKm * Whh2[Rf*HID + j]);
            f2h_go[j] = mk2(tKm * Whh2[Rg*HID + j], sKm * Whh2[Ro*HID + j]);
        }
        v2f fb1_if = mk2(sKm * (bih1[Ri] + bhh1[Ri]), sKm * (bih1[Rf] + bhh1[Rf]));
        v2f fb1_go = mk2(tKm * (bih1[Rg] + bhh1[Rg]), sKm * (bih1[Ro] + bhh1[Ro]));
        v2f fb2_if = mk2(sKm * (bih2[Ri] + bhh2[Ri]), sKm * (bih2[Rf] + bhh2[Rf]));
        v2f fb2_go = mk2(tKm * (bih2[Rg] + bhh2[Rg]), sKm * (bih2[Ro] + bhh2[Ro]));
        v2f fwx_if = mk2(sKm * Wih1[Ri], sKm * Wih1[Rf]);
        v2f fwx_go = mk2(tKm * Wih1[Rg], sKm * Wih1[Ro]);

        float h1b[10];
        c1 = stC1[lane];
        c2 = stC2[lane];
        loadhb(&stH1[e*16], h1b);
        loadhb(&stH2[e*16], h2b);

        auto fstep = [&](float yt) -> float {
            v2f A_if = dotp(f1_if, h1b, pfma2(fwx_if, mk2(yt, yt), fb1_if));
            v2f A_go = dotp(f1_go, h1b, pfma2(fwx_go, mk2(yt, yt), fb1_go));
            float h1n = cellup2(A_if, A_go, c1);
            bcast10(h1n, h1b);
            v2f U_if = dotp(f2i_if, h1b, fb2_if);
            v2f U_go = dotp(f2i_go, h1b, fb2_go);
            v2f V_if = dotp(f2h_if, h2b, mk2(U_if.x, U_if.y));
            v2f V_go = dotp(f2h_go, h2b, mk2(U_go.x, U_go.y));
            float h2n = cellup2(V_if, V_go, c2);
            bcast10(h2n, h2b);
            return head_();
        };

        float yp = yprev;
        int t = 0;
        #pragma unroll 1
        for (; t + 3 < F; t += 4) {
            float y0 = fstep(yp);
            float y1 = fstep(y0);
            float y2 = fstep(y1);
            float y3 = fstep(y2);
            if (u == 0) orow[(TMAIN + t) / 4] = make_float4(y0, y1, y2, y3);
            yp = y3;
        }
        #pragma unroll 1
        for (; t < F; ++t) {
            yp = fstep(yp);
            if (u == 0) out[(size_t)ge * OUTW + TMAIN + t] = yp;
        }
    }
}

extern "C" void kernel_launch(void* const* d_in, const int* in_sizes, int n_in,
                              void* d_out, int out_size, void* d_ws, size_t ws_size,
                              hipStream_t stream) {
    const float* x    = (const float*)d_in[0];
    const float* Wih1 = (const float*)d_in[1];
    const float* Whh1 = (const float*)d_in[2];
    const float* bih1 = (const float*)d_in[3];
    const float* bhh1 = (const float*)d_in[4];
    const float* Wih2 = (const float*)d_in[5];
    const float* Whh2 = (const float*)d_in[6];
    const float* bih2 = (const float*)d_in[7];
    const float* bhh2 = (const float*)d_in[8];
    const float* Wlin = (const float*)d_in[9];
    const float* blin = (const float*)d_in[10];
    const int*   futp = (const int*)d_in[11];
    float* out = (float*)d_out;

    lstm2_kernel<<<NB, 256, 0, stream>>>(x, Wih1, Whh1, bih1, bhh1,
                                         Wih2, Whh2, bih2, bhh2,
                                         Wlin, blin, futp, out);
}

// Round 13
// 321.023 us; speedup vs baseline: 1.1873x; 1.1873x over previous
//
#include <hip/hip_runtime.h>

// 2-layer LSTM (HID=10), B=2048, T=1024 main + F=64 future steps.
//
// Round 20: role-parity permutation on the r18 kernel (best, 274us).
// r19 post-mortem: +108 issue-cyc/SIMD/step -> +130 wall => the serial-role
// SIMDs are issue/exec-SATURATED; chain fixes buy nothing there. r18's wall
// (600 cyc/step, 2x the ~300 serial-wave exec) is two serial waves
// time-sharing one SIMD: co-resident blocks both map wid k -> SIMD k, so
// SIMD0 gets 2x cell1, SIMD2 gets 2x cell2 (saturated) while SIMD1/3 idle
// at ~15-20% (avg VALUBusy 51%). Fix with ONE line: odd blocks permute
// roles (role = wid ^ 1): even block SIMDs {cell1,U,cell2,head}, odd block
// {U,cell1,head,cell2} -> EVERY SIMD pairs one serial + one light wave.
// Serial throughput doubles; everything else verbatim r18 (math identical,
// absmax exactly 6.103516e-05).
// Predicted: wall 600 -> ~330-400 cyc/step, dur ~170-210us, VALUBusy 65-80%.

#define NB 512
#define TMAIN 1024
#define HID 10
#define KCH 16
#define NCH (TMAIN / KCH)   // 64 chunks

typedef float v2f __attribute__((ext_vector_type(2)));
typedef float v4f __attribute__((ext_vector_type(4)));

#define PIN2(v) asm volatile("" : "+v"(v))
#define PIN(v)  asm volatile("" : "+v"(v))

__device__ __forceinline__ float rcp_(float v)  { return __builtin_amdgcn_rcpf(v); }
__device__ __forceinline__ float exp2_(float v) { return __builtin_amdgcn_exp2f(v); }
__device__ __forceinline__ v2f mk2(float x, float y) { v2f r; r.x = x; r.y = y; return r; }
__device__ __forceinline__ v2f pfma2(v2f a, v2f b, v2f c) { return __builtin_elementwise_fma(a, b, c); }

template<int J>
__device__ __forceinline__ float bc16(float v) {   // broadcast lane J within each 16-group
    return __int_as_float(__builtin_amdgcn_ds_swizzle(__float_as_int(v), (J << 5) | 0x10));
}
__device__ __forceinline__ void bcast10(float h, float* hb) {
    hb[0] = bc16<0>(h); hb[1] = bc16<1>(h); hb[2] = bc16<2>(h); hb[3] = bc16<3>(h);
    hb[4] = bc16<4>(h); hb[5] = bc16<5>(h); hb[6] = bc16<6>(h); hb[7] = bc16<7>(h);
    hb[8] = bc16<8>(h); hb[9] = bc16<9>(h);
}

__global__ __launch_bounds__(256)
void lstm2_kernel(
    const float* __restrict__ x,
    const float* __restrict__ Wih1, const float* __restrict__ Whh1,
    const float* __restrict__ bih1, const float* __restrict__ bhh1,
    const float* __restrict__ Wih2, const float* __restrict__ Whh2,
    const float* __restrict__ bih2, const float* __restrict__ bhh2,
    const float* __restrict__ Wlin, const float* __restrict__ blin,
    const int* __restrict__ futp,
    float* __restrict__ out)
{
    const int tid  = threadIdx.x;
    const int wid  = tid >> 6;
    // Role-parity permutation: odd blocks swap (cell1<->U) and (cell2<->head)
    // so each SIMD hosts one serial + one light wave (2 blocks/CU).
    const int role = (blockIdx.x & 1) ? (wid ^ 1) : wid;   // 0=cell1 1=U 2=cell2 3=head
    const int lane = tid & 63;
    const int e    = lane >> 4;          // element 0..3
    const int u    = lane & 15;          // unit (valid < 10)
    const int ge   = blockIdx.x * 4 + e;
    const int F    = futp[0];
    const int OUTW = TMAIN + F;

    __shared__ __align__(16) float ringH1[2][KCH][64];  // h1(t) lanes
    __shared__ __align__(16) v4f   ringU [2][KCH][64];  // U(t) pre-acts
    __shared__ __align__(16) float ringH2[2][KCH][64];  // h2(t) lanes
    __shared__ __align__(16) float stC1[64], stH1[64], stC2[64], stH2[64];

    const bool uok = (u < HID);
    const int  uu  = uok ? u : 0;
    const int  Ri  = 0 * HID + uu;
    const int  Rf  = 1 * HID + uu;
    const int  Rg  = 2 * HID + uu;
    const int  Ro  = 3 * HID + uu;

    const float tK = 2.8853900817779268f;    //  2*log2(e)
    const float sK = -1.4426950408889634f;   // -log2(e)
    const float mu = uok ? 1.f : 0.f;
    const float sKm = mu * sK;
    const float tKm = mu * tK;

    // ---- per-lane weights, (i,f)/(g,o) v2f pairs, prescaled (all waves) ----
    v2f w1_if[10], w1_go[10], w2i_if[10], w2i_go[10], w2h_if[10], w2h_go[10];
    v2f wlp[5];
    #pragma unroll
    for (int j = 0; j < HID; ++j) {
        w1_if[j]  = mk2(sKm * Whh1[Ri*HID + j], sKm * Whh1[Rf*HID + j]);
        w1_go[j]  = mk2(tKm * Whh1[Rg*HID + j], sKm * Whh1[Ro*HID + j]);
        w2i_if[j] = mk2(sKm * Wih2[Ri*HID + j], sKm * Wih2[Rf*HID + j]);
        w2i_go[j] = mk2(tKm * Wih2[Rg*HID + j], sKm * Wih2[Ro*HID + j]);
        w2h_if[j] = mk2(sKm * Whh2[Ri*HID + j], sKm * Whh2[Rf*HID + j]);
        w2h_go[j] = mk2(tKm * Whh2[Rg*HID + j], sKm * Whh2[Ro*HID + j]);
    }
    #pragma unroll
    for (int k = 0; k < 5; ++k) wlp[k] = mk2(Wlin[2*k], Wlin[2*k + 1]);
    v2f b1_if = mk2(sKm * (bih1[Ri] + bhh1[Ri]), sKm * (bih1[Rf] + bhh1[Rf]));
    v2f b1_go = mk2(tKm * (bih1[Rg] + bhh1[Rg]), sKm * (bih1[Ro] + bhh1[Ro]));
    v2f b2_if = mk2(sKm * (bih2[Ri] + bhh2[Ri]), sKm * (bih2[Rf] + bhh2[Rf]));
    v2f b2_go = mk2(tKm * (bih2[Rg] + bhh2[Rg]), sKm * (bih2[Ro] + bhh2[Ro]));
    v2f wx_if = mk2(sKm * Wih1[Ri], sKm * Wih1[Rf]);
    v2f wx_go = mk2(tKm * Wih1[Rg], sKm * Wih1[Ro]);
    float bl = blin[0];

    #pragma unroll
    for (int j = 0; j < HID; ++j) {
        PIN2(w1_if[j]); PIN2(w1_go[j]); PIN2(w2i_if[j]); PIN2(w2i_go[j]);
        PIN2(w2h_if[j]); PIN2(w2h_go[j]);
    }
    #pragma unroll
    for (int k = 0; k < 5; ++k) PIN2(wlp[k]);
    PIN2(b1_if); PIN2(b1_go); PIN2(b2_if); PIN2(b2_go); PIN2(wx_if); PIN2(wx_go); PIN(bl);

    auto ctanh_ = [&](float cs) -> float {
        return fmaf(-2.0f, rcp_(1.0f + exp2_(cs)), 1.0f);
    };
    auto cellup2 = [&](v2f p_if, v2f p_go, float& c) -> float {   // verbatim r17
        v2f q_if, q_go;
        q_if.x = rcp_(1.0f + exp2_(p_if.x));
        q_if.y = rcp_(1.0f + exp2_(p_if.y));
        q_go.x = rcp_(1.0f + exp2_(p_go.x));
        q_go.y = rcp_(1.0f + exp2_(p_go.y));
        float g = fmaf(-2.0f * tK, q_go.x, tK);
        c = fmaf(q_if.y, c, q_if.x * g);
        return q_go.y * ctanh_(c);
    };
    auto dotp = [&](const v2f* w, const float* hb, v2f init) -> v2f {  // verbatim r17
        v2f P = pfma2(w[0], mk2(hb[0], hb[0]), init);
        v2f Q = w[1] * mk2(hb[1], hb[1]);
        #pragma unroll
        for (int j = 2; j < HID; j += 2) {
            P = pfma2(w[j],     mk2(hb[j],     hb[j]),     P);
            Q = pfma2(w[j + 1], mk2(hb[j + 1], hb[j + 1]), Q);
        }
        return P + Q;
    };
    // uniform-address broadcast load of 10 floats (per 16-group base)
    auto loadhb = [&](const float* base, float* hb) {
        v4f a = *(const v4f*)(base);
        v4f b = *(const v4f*)(base + 4);
        v2f c = *(const v2f*)(base + 8);
        hb[0] = a.x; hb[1] = a.y; hb[2] = a.z; hb[3] = a.w;
        hb[4] = b.x; hb[5] = b.y; hb[6] = b.z; hb[7] = b.w;
        hb[8] = c.x; hb[9] = c.y;
    };

    // ---- state ----
    float c1 = 0.f, c2 = 0.f, h1last = 0.f, h2last = 0.f, yprev = 0.f;
    float h1b[10], h2b[10];
    #pragma unroll
    for (int j = 0; j < HID; ++j) { h1b[j] = 0.f; h2b[j] = 0.f; }

    auto head_ = [&]() -> float {                // verbatim r17
        v2f Y = pfma2(wlp[0], mk2(h2b[0], h2b[1]), mk2(bl, 0.f));
        #pragma unroll
        for (int k = 1; k < 5; ++k)
            Y = pfma2(wlp[k], mk2(h2b[2*k], h2b[2*k + 1]), Y);
        return Y.x + Y.y;
    };

    // W0: cell1 step -> h1 lane value to ring slot
    auto pstep0 = [&](float xt, float* hslot) -> float {
        v2f A_if = dotp(w1_if, h1b, pfma2(wx_if, mk2(xt, xt), b1_if));
        v2f A_go = dotp(w1_go, h1b, pfma2(wx_go, mk2(xt, xt), b1_go));
        float h1n = cellup2(A_if, A_go, c1);
        bcast10(h1n, h1b);
        hslot[lane] = h1n;
        return h1n;
    };
    // W3 future step (full serial cell1+U+cell2+head; values == r17 fstep)
    auto fstep = [&](float yt) -> float {
        v2f A_if = dotp(w1_if, h1b, pfma2(wx_if, mk2(yt, yt), b1_if));
        v2f A_go = dotp(w1_go, h1b, pfma2(wx_go, mk2(yt, yt), b1_go));
        float h1n = cellup2(A_if, A_go, c1);
        bcast10(h1n, h1b);
        v2f U_if = dotp(w2i_if, h1b, b2_if);
        v2f U_go = dotp(w2i_go, h1b, b2_go);
        v2f V_if = dotp(w2h_if, h2b, mk2(U_if.x, U_if.y));
        v2f V_go = dotp(w2h_go, h2b, mk2(U_go.x, U_go.y));
        float h2n = cellup2(V_if, V_go, c2);
        bcast10(h2n, h2b);
        return head_();
    };

    const float4* xrow = (const float4*)(x + (size_t)ge * TMAIN);
    float4* orow = (float4*)(out + (size_t)ge * OUTW);   // OUTW=1088, 16B rows

    float4 z4 = make_float4(0.f, 0.f, 0.f, 0.f);
    float4 xq0 = z4, xq1 = z4, xq2 = z4, xq3 = z4;
    if (role == 0) { xq0 = xrow[0]; xq1 = xrow[1]; xq2 = xrow[2]; xq3 = xrow[3]; }

    // ---- main pipeline: 67 iterations; role k processes chunk c-k ----
    #pragma unroll 1
    for (int c = 0; c <= NCH + 2; ++c) {
        if (role == 0) {
            if (c < NCH) {
                float4 xn0 = z4, xn1 = z4, xn2 = z4, xn3 = z4;
                if (c + 1 < NCH) {
                    xn0 = xrow[(c+1)*4+0]; xn1 = xrow[(c+1)*4+1];
                    xn2 = xrow[(c+1)*4+2]; xn3 = xrow[(c+1)*4+3];
                }
                float* hs = &ringH1[c & 1][0][0];
                h1last = pstep0(xq0.x, hs + 0*64);  h1last = pstep0(xq0.y, hs + 1*64);
                h1last = pstep0(xq0.z, hs + 2*64);  h1last = pstep0(xq0.w, hs + 3*64);
                h1last = pstep0(xq1.x, hs + 4*64);  h1last = pstep0(xq1.y, hs + 5*64);
                h1last = pstep0(xq1.z, hs + 6*64);  h1last = pstep0(xq1.w, hs + 7*64);
                h1last = pstep0(xq2.x, hs + 8*64);  h1last = pstep0(xq2.y, hs + 9*64);
                h1last = pstep0(xq2.z, hs + 10*64); h1last = pstep0(xq2.w, hs + 11*64);
                h1last = pstep0(xq3.x, hs + 12*64); h1last = pstep0(xq3.y, hs + 13*64);
                h1last = pstep0(xq3.z, hs + 14*64); h1last = pstep0(xq3.w, hs + 15*64);
                if (c == NCH - 1) { stC1[lane] = c1; stH1[lane] = h1last; }
                xq0 = xn0; xq1 = xn1; xq2 = xn2; xq3 = xn3;
            }
        } else if (role == 1) {
            const int cc = c - 1;
            if (cc >= 0 && cc < NCH) {
                const float* hs = &ringH1[cc & 1][0][0];
                v4f* us = &ringU[cc & 1][0][0];
                #pragma unroll
                for (int t = 0; t < KCH; ++t) {
                    float hb[10];
                    loadhb(hs + t*64 + e*16, hb);
                    v2f U_if = dotp(w2i_if, hb, b2_if);
                    v2f U_go = dotp(w2i_go, hb, b2_go);
                    v4f U; U.x = U_if.x; U.y = U_if.y; U.z = U_go.x; U.w = U_go.y;
                    us[t*64 + lane] = U;
                }
            }
        } else if (role == 2) {
            const int cc = c - 2;
            if (cc >= 0 && cc < NCH) {
                const v4f* us = &ringU[cc & 1][0][0];
                float* h2s = &ringH2[cc & 1][0][0];
                #pragma unroll
                for (int t = 0; t < KCH; ++t) {
                    v4f U = us[t*64 + lane];
                    v2f V_if = dotp(w2h_if, h2b, mk2(U.x, U.y));
                    v2f V_go = dotp(w2h_go, h2b, mk2(U.z, U.w));
                    float h2n = cellup2(V_if, V_go, c2);
                    bcast10(h2n, h2b);
                    h2s[t*64 + lane] = h2n;
                    h2last = h2n;
                }
                if (cc == NCH - 1) { stC2[lane] = c2; stH2[lane] = h2last; }
            }
        } else {
            const int cc = c - 3;
            if (cc >= 0 && cc < NCH) {
                const float* h2s = &ringH2[cc & 1][0][0];
                #pragma unroll
                for (int q = 0; q < 4; ++q) {
                    float y0, y1, y2, y3;
                    loadhb(h2s + (q*4 + 0)*64 + e*16, h2b); y0 = head_();
                    loadhb(h2s + (q*4 + 1)*64 + e*16, h2b); y1 = head_();
                    loadhb(h2s + (q*4 + 2)*64 + e*16, h2b); y2 = head_();
                    loadhb(h2s + (q*4 + 3)*64 + e*16, h2b); y3 = head_();
                    if (u == 0) orow[cc*4 + q] = make_float4(y0, y1, y2, y3);
                    yprev = y3;
                }
            }
        }
        __syncthreads();
    }

    // ---- future loop: head role only, fully serial (y feeds back) ----
    if (role == 3) {
        c1 = stC1[lane];
        c2 = stC2[lane];
        loadhb(&stH1[e*16], h1b);
        loadhb(&stH2[e*16], h2b);
        float yp = yprev;
        int t = 0;
        #pragma unroll 1
        for (; t + 3 < F; t += 4) {
            float y0 = fstep(yp);
            float y1 = fstep(y0);
            float y2 = fstep(y1);
            float y3 = fstep(y2);
            if (u == 0) orow[(TMAIN + t) / 4] = make_float4(y0, y1, y2, y3);
            yp = y3;
        }
        #pragma unroll 1
        for (; t < F; ++t) {
            yp = fstep(yp);
            if (u == 0) out[(size_t)ge * OUTW + TMAIN + t] = yp;
        }
    }
}

extern "C" void kernel_launch(void* const* d_in, const int* in_sizes, int n_in,
                              void* d_out, int out_size, void* d_ws, size_t ws_size,
                              hipStream_t stream) {
    const float* x    = (const float*)d_in[0];
    const float* Wih1 = (const float*)d_in[1];
    const float* Whh1 = (const float*)d_in[2];
    const float* bih1 = (const float*)d_in[3];
    const float* bhh1 = (const float*)d_in[4];
    const float* Wih2 = (const float*)d_in[5];
    const float* Whh2 = (const float*)d_in[6];
    const float* bih2 = (const float*)d_in[7];
    const float* bhh2 = (const float*)d_in[8];
    const float* Wlin = (const float*)d_in[9];
    const float* blin = (const float*)d_in[10];
    const int*   futp = (const int*)d_in[11];
    float* out = (float*)d_out;

    lstm2_kernel<<<NB, 256, 0, stream>>>(x, Wih1, Whh1, bih1, bhh1,
                                         Wih2, Whh2, bih2, bhh2,
                                         Wlin, blin, futp, out);
}